// Round 8
// baseline (7422.631 us; speedup 1.0000x reference)
//
#include <hip/hip_runtime.h>

// SurfSageEncoder: 3x SAGEConv(mean) + linear head, fp32.
// N=50000 nodes, E=600000 edges, D: 128 -> 128 -> 128 -> 64 -> 64.
//
// R8 == R6 == R7 (never benched: repeated GPU acquisition timeouts).
// GEMM = R2 structure (only one measured clean: 78us, WRITE==output,
// VGPR 84). global_load_lds REMOVED — R3/R5 disasters trace to its
// per-lane-varying LDS destination (must be wave-uniform per m104) =>
// waterfall lowering => VGPR 256 + GB-scale scratch traffic.
// Changes vs R2, each individually verified or free:
//  - Bt staging j=tid%COLS, row stride COLS+4 (conflicts 5.6M -> 0 in R3/R5)
//  - As unpadded stride 32: staging = consecutive 16B/lane (bandwidth),
//    compute reads = 2-addr broadcast (2-way = free)
//  - 32-row tiles: grid 782 -> 1563 blocks (R2 occupancy was grid-capped at
//    3 blocks/CU, 19%)
//  - single-buffered, no dynamic LDS buffer index anywhere.

#define BLK 256

// ---------------- CSR build ----------------

__global__ __launch_bounds__(BLK) void k_hist(const int* __restrict__ dst,
                                              int* __restrict__ deg, int E) {
  int i = blockIdx.x * BLK + threadIdx.x;
  int stride = gridDim.x * BLK;
  for (; i < E; i += stride) atomicAdd(&deg[dst[i]], 1);
}

__global__ __launch_bounds__(BLK) void k_scan1(const int* __restrict__ deg,
                                               int* __restrict__ offs,
                                               int* __restrict__ bsums, int n) {
  __shared__ int lds[BLK];
  int t = threadIdx.x;
  int base = blockIdx.x * 1024 + t * 4;
  int v0 = (base + 0 < n) ? deg[base + 0] : 0;
  int v1 = (base + 1 < n) ? deg[base + 1] : 0;
  int v2 = (base + 2 < n) ? deg[base + 2] : 0;
  int v3 = (base + 3 < n) ? deg[base + 3] : 0;
  int s = v0 + v1 + v2 + v3;
  lds[t] = s;
  __syncthreads();
  for (int off = 1; off < BLK; off <<= 1) {
    int x = 0;
    if (t >= off) x = lds[t - off];
    __syncthreads();
    if (t >= off) lds[t] += x;
    __syncthreads();
  }
  int excl = lds[t] - s;
  if (base + 0 < n) offs[base + 0] = excl;
  if (base + 1 < n) offs[base + 1] = excl + v0;
  if (base + 2 < n) offs[base + 2] = excl + v0 + v1;
  if (base + 3 < n) offs[base + 3] = excl + v0 + v1 + v2;
  if (t == BLK - 1) bsums[blockIdx.x] = lds[BLK - 1];
}

__global__ void k_scan2(int* __restrict__ bsums, int nb) {
  if (blockIdx.x == 0 && threadIdx.x == 0) {
    int acc = 0;
    for (int i = 0; i < nb; ++i) { int v = bsums[i]; bsums[i] = acc; acc += v; }
  }
}

__global__ __launch_bounds__(BLK) void k_scan3(int* __restrict__ offs,
                                               const int* __restrict__ bsums,
                                               int* __restrict__ cursor, int n, int E) {
  int i = blockIdx.x * BLK + threadIdx.x;
  if (i < n) {
    int o = offs[i] + bsums[i >> 10];
    offs[i] = o;
    cursor[i] = o;
  }
  if (i == 0) offs[n] = E;
}

__global__ __launch_bounds__(BLK) void k_fill(const int* __restrict__ src,
                                              const int* __restrict__ dst,
                                              int* __restrict__ cursor,
                                              int* __restrict__ csr, int E) {
  int i = blockIdx.x * BLK + threadIdx.x;
  int stride = gridDim.x * BLK;
  for (; i < E; i += stride) {
    int p = atomicAdd(&cursor[dst[i]], 1);
    csr[p] = src[i];
  }
}

// ---------------- mean aggregation: one wave per node, D=128 ----------------

__global__ __launch_bounds__(BLK) void k_agg(const float* __restrict__ in,
                                             const int* __restrict__ offs,
                                             const int* __restrict__ csr,
                                             float* __restrict__ outmean, int n) {
  int wid = (blockIdx.x * BLK + threadIdx.x) >> 6;
  int lane = threadIdx.x & 63;
  if (wid >= n) return;
  int beg = offs[wid], end = offs[wid + 1];
  const float2* in2 = (const float2*)in;
  float ax = 0.f, ay = 0.f;
  int e = beg;
  for (; e + 3 < end; e += 4) {  // 4 rows in flight
    int s0 = csr[e], s1 = csr[e + 1], s2 = csr[e + 2], s3 = csr[e + 3];
    float2 a = in2[s0 * 64 + lane];
    float2 b = in2[s1 * 64 + lane];
    float2 c = in2[s2 * 64 + lane];
    float2 d = in2[s3 * 64 + lane];
    ax += a.x + b.x + c.x + d.x;
    ay += a.y + b.y + c.y + d.y;
  }
  for (; e < end; ++e) {
    int s = csr[e];
    float2 a = in2[s * 64 + lane];
    ax += a.x; ay += a.y;
  }
  int d = end - beg;
  float inv = 1.0f / (float)(d > 0 ? d : 1);
  float2 r; r.x = ax * inv; r.y = ay * inv;
  ((float2*)outmean)[wid * 64 + lane] = r;
}

// 64-dim mean-agg of P (cols 0..63 of PQ) plus Q (cols 64..127).
__global__ __launch_bounds__(BLK) void k_agg_add(const float* __restrict__ PQ,
                                                 const int* __restrict__ offs,
                                                 const int* __restrict__ csr,
                                                 float* __restrict__ outv, int n) {
  int wid = (blockIdx.x * BLK + threadIdx.x) >> 6;
  int lane = threadIdx.x & 63;
  if (wid >= n) return;
  int beg = offs[wid], end = offs[wid + 1];
  float a = 0.f;
  int e = beg;
  for (; e + 3 < end; e += 4) {
    int s0 = csr[e], s1 = csr[e + 1], s2 = csr[e + 2], s3 = csr[e + 3];
    a += PQ[s0 * 128 + lane] + PQ[s1 * 128 + lane] +
         PQ[s2 * 128 + lane] + PQ[s3 * 128 + lane];
  }
  for (; e < end; ++e) a += PQ[csr[e] * 128 + lane];
  int d = end - beg;
  float inv = 1.0f / (float)(d > 0 ? d : 1);
  outv[wid * 64 + lane] = a * inv + PQ[wid * 128 + 64 + lane];
}

// ---------------- fused linear GEMM (single-buffered, 32-row tiles) --------
// out[32 rows x COLS] per block. Slabs 0..NS0-1: A0@W0^T; NS0..: A1@W1^T.
// DUAL: one phase over K0; cols<64 from W0 (no bias), cols>=64 from W1
// (+bias). A staged global->reg->LDS As[32][32] (write = consecutive 16B/
// lane; compute read = 2-addr broadcast, free). W staged into transposed
// Bt[32][COLS+4], j=tid%COLS (2-way writes = free; verified 0 conflicts).

template <int COLS, int NS0, int NS1, bool RELU, bool DUAL>
__global__ __launch_bounds__(BLK) void k_linear(
    const float* __restrict__ A0, const float* __restrict__ W0,
    const float* __restrict__ A1, const float* __restrict__ W1,
    const float* __restrict__ bias, float* __restrict__ out, int M) {
  constexpr int KT = 32;
  constexpr int ROWS = 32;
  constexpr int NSLAB = NS0 + NS1;
  constexpr int K0 = NS0 * KT;
  constexpr int K1 = NS1 * KT;
  constexpr int TC = COLS / 4;            // 32 or 16
  constexpr int TR = BLK / TC;            // 8 or 16
  constexpr int RPT = ROWS / TR;          // 4 or 2
  constexpr int BTS = COLS + 4;           // 16B-aligned, bank-spread
  constexpr int KSPAN = KT * COLS / BLK;  // 16 or 8
  constexpr int F = KSPAN / 4;            // 4 or 2

  __shared__ float As[ROWS * KT];         // 4 KB
  __shared__ float Bt[KT * BTS];          // 16.5/8.5 KB

  const int tid = threadIdx.x;
  const int tc = tid % TC, tr = tid / TC;
  const int j0 = tc * 4;
  const int rbase = tr * RPT;
  const int growbase = blockIdx.x * ROWS;

  // A staging: thread t covers float4 #t of the 256-float4 tile
  const int arow = tid >> 3;              // 0..31
  const int asg = tid & 7;                // 16B segment within row

  // Bt staging
  const int bj = tid % COLS;
  const int kq = (tid / COLS) * KSPAN;

  float4 acc[RPT];
#pragma unroll
  for (int rr = 0; rr < RPT; ++rr) acc[rr] = make_float4(0.f, 0.f, 0.f, 0.f);

#pragma unroll
  for (int s = 0; s < NSLAB; ++s) {
    const float* Ap = (s < NS0) ? A0 : A1;
    const int KA = (s < NS0) ? K0 : K1;
    const int kb = ((s < NS0) ? s : s - NS0) * KT;

    // stage A: one float4 per thread
    {
      const int gr = growbase + arow;
      float4 v = make_float4(0.f, 0.f, 0.f, 0.f);
      if (gr < M) v = *(const float4*)&Ap[(size_t)gr * KA + kb + asg * 4];
      *(float4*)&As[arow * KT + asg * 4] = v;
    }
    // stage Bt (transposed W slab)
    {
      const float* Wrow;
      if (DUAL)
        Wrow = (bj < 64) ? (W0 + (size_t)bj * K0) : (W1 + (size_t)(bj - 64) * K0);
      else
        Wrow = (s < NS0) ? (W0 + (size_t)bj * K0) : (W1 + (size_t)bj * K1);
#pragma unroll
      for (int f = 0; f < F; ++f) {
        const float4 w = *(const float4*)&Wrow[kb + kq + f * 4];
        const int kk = kq + f * 4;
        Bt[(kk + 0) * BTS + bj] = w.x;
        Bt[(kk + 1) * BTS + bj] = w.y;
        Bt[(kk + 2) * BTS + bj] = w.z;
        Bt[(kk + 3) * BTS + bj] = w.w;
      }
    }
    __syncthreads();

#pragma unroll
    for (int kk = 0; kk < KT; kk += 4) {
      float4 a4[RPT];
#pragma unroll
      for (int rr = 0; rr < RPT; ++rr)
        a4[rr] = *(const float4*)&As[(rbase + rr) * KT + kk];
#pragma unroll
      for (int dk = 0; dk < 4; ++dk) {
        const float4 bv = *(const float4*)&Bt[(kk + dk) * BTS + j0];
#pragma unroll
        for (int rr = 0; rr < RPT; ++rr) {
          const float av = (dk == 0)   ? a4[rr].x
                           : (dk == 1) ? a4[rr].y
                           : (dk == 2) ? a4[rr].z
                                       : a4[rr].w;
          acc[rr].x += av * bv.x;
          acc[rr].y += av * bv.y;
          acc[rr].z += av * bv.z;
          acc[rr].w += av * bv.w;
        }
      }
    }
    __syncthreads();
  }

  float4 bv4 = make_float4(0.f, 0.f, 0.f, 0.f);
  if (!DUAL) {
    bv4 = *(const float4*)&bias[j0];
  } else if (j0 >= 64) {
    bv4 = *(const float4*)&bias[j0 - 64];
  }
#pragma unroll
  for (int rr = 0; rr < RPT; ++rr) {
    const int gr = growbase + rbase + rr;
    if (gr < M) {
      float4 o = acc[rr];
      o.x += bv4.x; o.y += bv4.y; o.z += bv4.z; o.w += bv4.w;
      if (RELU) {
        o.x = fmaxf(o.x, 0.f); o.y = fmaxf(o.y, 0.f);
        o.z = fmaxf(o.z, 0.f); o.w = fmaxf(o.w, 0.f);
      }
      *(float4*)&out[(size_t)gr * COLS + j0] = o;
    }
  }
}

// ---------------- launch ----------------

extern "C" void kernel_launch(void* const* d_in, const int* in_sizes, int n_in,
                              void* d_out, int out_size, void* d_ws, size_t ws_size,
                              hipStream_t stream) {
  const float* x    = (const float*)d_in[0];
  const int*   edge = (const int*)d_in[1];
  const float* Wl1  = (const float*)d_in[2];
  const float* bl1  = (const float*)d_in[3];
  const float* Wr1  = (const float*)d_in[4];
  const float* Wl2  = (const float*)d_in[5];
  const float* bl2  = (const float*)d_in[6];
  const float* Wr2  = (const float*)d_in[7];
  const float* Wl3  = (const float*)d_in[8];
  const float* bl3  = (const float*)d_in[9];
  const float* Wr3  = (const float*)d_in[10];
  const float* Wreg = (const float*)d_in[11];
  const float* breg = (const float*)d_in[12];

  const int N = in_sizes[0] / 128;  // 50000
  const int E = in_sizes[1] / 2;    // 600000
  const int* src = edge;
  const int* dst = edge + E;

  char* ws = (char*)d_ws;
  size_t off = 0;
  auto alloc = [&](size_t bytes) {
    void* p = ws + off;
    off = (off + bytes + 255) & ~(size_t)255;
    return p;
  };
  int*   deg    = (int*)alloc((size_t)N * 4);
  int*   offs   = (int*)alloc((size_t)(N + 1) * 4);
  int*   cursor = (int*)alloc((size_t)N * 4);
  int*   csr    = (int*)alloc((size_t)E * 4);
  int*   bsums  = (int*)alloc(256 * 4);
  float* mean   = (float*)alloc((size_t)N * 128 * 4);  // also PQ buffer (layer 3)
  float* hA     = (float*)alloc((size_t)N * 128 * 4);
  float* hB     = (float*)alloc((size_t)N * 128 * 4);
  (void)ws_size;

  // --- CSR build ---
  hipMemsetAsync(deg, 0, (size_t)N * 4, stream);
  k_hist<<<2048, BLK, 0, stream>>>(dst, deg, E);
  int nb = (N + 1023) >> 10;
  k_scan1<<<nb, BLK, 0, stream>>>(deg, offs, bsums, N);
  k_scan2<<<1, 64, 0, stream>>>(bsums, nb);
  k_scan3<<<(N + BLK - 1) / BLK, BLK, 0, stream>>>(offs, bsums, cursor, N, E);
  k_fill<<<2048, BLK, 0, stream>>>(src, dst, cursor, csr, E);

  const int aggGrid = (N * 64 + BLK - 1) / BLK;
  const int gemmGrid = (N + 31) / 32;   // 32-row tiles

  // --- layer 1: h1 = relu(mean(x)@Wl1^T + x@Wr1^T + bl1) ---
  k_agg<<<aggGrid, BLK, 0, stream>>>(x, offs, csr, mean, N);
  k_linear<128, 4, 4, true, false><<<gemmGrid, BLK, 0, stream>>>(
      mean, Wl1, x, Wr1, bl1, hA, N);

  // --- layer 2 ---
  k_agg<<<aggGrid, BLK, 0, stream>>>(hA, offs, csr, mean, N);
  k_linear<128, 4, 4, true, false><<<gemmGrid, BLK, 0, stream>>>(
      mean, Wl2, hA, Wr2, bl2, hB, N);

  // --- layer 3 (transform-before-aggregate): PQ = [hB@Wl3^T | hB@Wr3^T+bl3] ---
  k_linear<128, 4, 0, false, true><<<gemmGrid, BLK, 0, stream>>>(
      hB, Wl3, (const float*)nullptr, Wr3, bl3, mean, N);
  k_agg_add<<<aggGrid, BLK, 0, stream>>>(mean, offs, csr, hA, N);

  // --- head: out = h3@Wreg^T + breg ---
  k_linear<64, 2, 0, false, false><<<gemmGrid, BLK, 0, stream>>>(
      hA, Wreg, (const float*)nullptr, (const float*)nullptr, breg,
      (float*)d_out, N);
}

// Round 10
// 433.563 us; speedup vs baseline: 17.1201x; 17.1201x over previous
//
#include <hip/hip_runtime.h>

// SurfSageEncoder: 3x SAGEConv(mean) + linear head, fp32.
// N=50000 nodes, E=600000 edges, D: 128 -> 128 -> 128 -> 64 -> 64.
//
// R10 == R9 (never benched: GPU acquisition timeout).
// Spill root cause (R3/R5/R8): compile-time slab count + full unroll
// => scheduler hoists all 8 slabs' global loads (160+ VGPRs in flight) =>
// VGPR cap 256 => acc spills => GB-scale scratch FETCH/WRITE, VALUBusy ~1.5%.
// R2 (VGPR 84, clean) had RUNTIME K-loop bounds. This version: runtime K0/K1
// phase loops (no unroll), keeping R8's measured-good staging maps
// (SQ_LDS_BANK_CONFLICT == 0) and 32-row tiles.

#define BLK 256

// ---------------- CSR build ----------------

__global__ __launch_bounds__(BLK) void k_hist(const int* __restrict__ dst,
                                              int* __restrict__ deg, int E) {
  int i = blockIdx.x * BLK + threadIdx.x;
  int stride = gridDim.x * BLK;
  for (; i < E; i += stride) atomicAdd(&deg[dst[i]], 1);
}

__global__ __launch_bounds__(BLK) void k_scan1(const int* __restrict__ deg,
                                               int* __restrict__ offs,
                                               int* __restrict__ bsums, int n) {
  __shared__ int lds[BLK];
  int t = threadIdx.x;
  int base = blockIdx.x * 1024 + t * 4;
  int v0 = (base + 0 < n) ? deg[base + 0] : 0;
  int v1 = (base + 1 < n) ? deg[base + 1] : 0;
  int v2 = (base + 2 < n) ? deg[base + 2] : 0;
  int v3 = (base + 3 < n) ? deg[base + 3] : 0;
  int s = v0 + v1 + v2 + v3;
  lds[t] = s;
  __syncthreads();
  for (int off = 1; off < BLK; off <<= 1) {
    int x = 0;
    if (t >= off) x = lds[t - off];
    __syncthreads();
    if (t >= off) lds[t] += x;
    __syncthreads();
  }
  int excl = lds[t] - s;
  if (base + 0 < n) offs[base + 0] = excl;
  if (base + 1 < n) offs[base + 1] = excl + v0;
  if (base + 2 < n) offs[base + 2] = excl + v0 + v1;
  if (base + 3 < n) offs[base + 3] = excl + v0 + v1 + v2;
  if (t == BLK - 1) bsums[blockIdx.x] = lds[BLK - 1];
}

__global__ void k_scan2(int* __restrict__ bsums, int nb) {
  if (blockIdx.x == 0 && threadIdx.x == 0) {
    int acc = 0;
    for (int i = 0; i < nb; ++i) { int v = bsums[i]; bsums[i] = acc; acc += v; }
  }
}

__global__ __launch_bounds__(BLK) void k_scan3(int* __restrict__ offs,
                                               const int* __restrict__ bsums,
                                               int* __restrict__ cursor, int n, int E) {
  int i = blockIdx.x * BLK + threadIdx.x;
  if (i < n) {
    int o = offs[i] + bsums[i >> 10];
    offs[i] = o;
    cursor[i] = o;
  }
  if (i == 0) offs[n] = E;
}

__global__ __launch_bounds__(BLK) void k_fill(const int* __restrict__ src,
                                              const int* __restrict__ dst,
                                              int* __restrict__ cursor,
                                              int* __restrict__ csr, int E) {
  int i = blockIdx.x * BLK + threadIdx.x;
  int stride = gridDim.x * BLK;
  for (; i < E; i += stride) {
    int p = atomicAdd(&cursor[dst[i]], 1);
    csr[p] = src[i];
  }
}

// ---------------- mean aggregation: one wave per node, D=128 ----------------

__global__ __launch_bounds__(BLK) void k_agg(const float* __restrict__ in,
                                             const int* __restrict__ offs,
                                             const int* __restrict__ csr,
                                             float* __restrict__ outmean, int n) {
  int wid = (blockIdx.x * BLK + threadIdx.x) >> 6;
  int lane = threadIdx.x & 63;
  if (wid >= n) return;
  int beg = offs[wid], end = offs[wid + 1];
  const float2* in2 = (const float2*)in;
  float ax = 0.f, ay = 0.f;
  int e = beg;
  for (; e + 3 < end; e += 4) {  // 4 rows in flight
    int s0 = csr[e], s1 = csr[e + 1], s2 = csr[e + 2], s3 = csr[e + 3];
    float2 a = in2[s0 * 64 + lane];
    float2 b = in2[s1 * 64 + lane];
    float2 c = in2[s2 * 64 + lane];
    float2 d = in2[s3 * 64 + lane];
    ax += a.x + b.x + c.x + d.x;
    ay += a.y + b.y + c.y + d.y;
  }
  for (; e < end; ++e) {
    int s = csr[e];
    float2 a = in2[s * 64 + lane];
    ax += a.x; ay += a.y;
  }
  int d = end - beg;
  float inv = 1.0f / (float)(d > 0 ? d : 1);
  float2 r; r.x = ax * inv; r.y = ay * inv;
  ((float2*)outmean)[wid * 64 + lane] = r;
}

// 64-dim mean-agg of P (cols 0..63 of PQ) plus Q (cols 64..127).
__global__ __launch_bounds__(BLK) void k_agg_add(const float* __restrict__ PQ,
                                                 const int* __restrict__ offs,
                                                 const int* __restrict__ csr,
                                                 float* __restrict__ outv, int n) {
  int wid = (blockIdx.x * BLK + threadIdx.x) >> 6;
  int lane = threadIdx.x & 63;
  if (wid >= n) return;
  int beg = offs[wid], end = offs[wid + 1];
  float a = 0.f;
  int e = beg;
  for (; e + 3 < end; e += 4) {
    int s0 = csr[e], s1 = csr[e + 1], s2 = csr[e + 2], s3 = csr[e + 3];
    a += PQ[s0 * 128 + lane] + PQ[s1 * 128 + lane] +
         PQ[s2 * 128 + lane] + PQ[s3 * 128 + lane];
  }
  for (; e < end; ++e) a += PQ[csr[e] * 128 + lane];
  int d = end - beg;
  float inv = 1.0f / (float)(d > 0 ? d : 1);
  outv[wid * 64 + lane] = a * inv + PQ[wid * 128 + 64 + lane];
}

// ---------------- fused linear GEMM (runtime-K loops, 32-row tiles) --------
// out[32 rows x COLS] per block. Phase 0: A0@W0^T over runtime K0 (DUAL:
// cols<64 from W0 no-bias, cols>=64 from W1 +bias, both row-stride K0).
// Phase 1 (skipped when K1==0): A1@W1^T over runtime K1. Runtime loop bounds
// prevent full unroll / global-load hoisting (the R3/R5/R8 spill cause).
// A staged global->reg->LDS As[32][32]: lane writes contiguous 16B (conflict-
// free); compute reads are 2-addr broadcasts. W staged into transposed
// Bt[32][COLS+4], j=tid%COLS (measured 0 conflicts).

template <int COLS, bool RELU, bool DUAL>
__global__ __launch_bounds__(BLK) void k_linear(
    const float* __restrict__ A0, const float* __restrict__ W0, int K0,
    const float* __restrict__ A1, const float* __restrict__ W1, int K1,
    const float* __restrict__ bias, float* __restrict__ out, int M) {
  constexpr int KT = 32;
  constexpr int ROWS = 32;
  constexpr int TC = COLS / 4;            // 32 or 16
  constexpr int TR = BLK / TC;            // 8 or 16
  constexpr int RPT = ROWS / TR;          // 4 or 2
  constexpr int BTS = COLS + 4;           // 16B-aligned, bank-spread
  constexpr int KSPAN = KT * COLS / BLK;  // 16 or 8
  constexpr int F = KSPAN / 4;            // 4 or 2

  __shared__ float As[ROWS * KT];         // 4 KB
  __shared__ float Bt[KT * BTS];          // 16.5/8.5 KB

  const int tid = threadIdx.x;
  const int tc = tid % TC, tr = tid / TC;
  const int j0 = tc * 4;
  const int rbase = tr * RPT;
  const int growbase = blockIdx.x * ROWS;

  // A staging: thread t covers float4 #t of the 256-float4 tile (contiguous)
  const int arow = tid >> 3;              // 0..31
  const int asg = tid & 7;                // 16B segment within row

  // Bt staging
  const int bj = tid % COLS;
  const int kq = (tid / COLS) * KSPAN;

  float4 acc[RPT];
#pragma unroll
  for (int rr = 0; rr < RPT; ++rr) acc[rr] = make_float4(0.f, 0.f, 0.f, 0.f);

  // ---- phase 0: A0 @ W0^T (runtime K0) ----
  for (int k0 = 0; k0 < K0; k0 += KT) {
    {
      const int gr = growbase + arow;
      float4 v = make_float4(0.f, 0.f, 0.f, 0.f);
      if (gr < M) v = *(const float4*)&A0[(size_t)gr * K0 + k0 + asg * 4];
      *(float4*)&As[arow * KT + asg * 4] = v;
    }
    {
      const float* Wrow;
      if (DUAL)
        Wrow = (bj < 64) ? (W0 + (size_t)bj * K0) : (W1 + (size_t)(bj - 64) * K0);
      else
        Wrow = W0 + (size_t)bj * K0;
#pragma unroll
      for (int f = 0; f < F; ++f) {
        const float4 w = *(const float4*)&Wrow[k0 + kq + f * 4];
        const int kk = kq + f * 4;
        Bt[(kk + 0) * BTS + bj] = w.x;
        Bt[(kk + 1) * BTS + bj] = w.y;
        Bt[(kk + 2) * BTS + bj] = w.z;
        Bt[(kk + 3) * BTS + bj] = w.w;
      }
    }
    __syncthreads();
#pragma unroll
    for (int kk = 0; kk < KT; kk += 4) {
      float4 a4[RPT];
#pragma unroll
      for (int rr = 0; rr < RPT; ++rr)
        a4[rr] = *(const float4*)&As[(rbase + rr) * KT + kk];
#pragma unroll
      for (int dk = 0; dk < 4; ++dk) {
        const float4 bv = *(const float4*)&Bt[(kk + dk) * BTS + j0];
#pragma unroll
        for (int rr = 0; rr < RPT; ++rr) {
          const float av = (dk == 0)   ? a4[rr].x
                           : (dk == 1) ? a4[rr].y
                           : (dk == 2) ? a4[rr].z
                                       : a4[rr].w;
          acc[rr].x += av * bv.x;
          acc[rr].y += av * bv.y;
          acc[rr].z += av * bv.z;
          acc[rr].w += av * bv.w;
        }
      }
    }
    __syncthreads();
  }

  // ---- phase 1: A1 @ W1^T (runtime K1; trip 0 for DUAL/head) ----
  for (int k0 = 0; k0 < K1; k0 += KT) {
    {
      const int gr = growbase + arow;
      float4 v = make_float4(0.f, 0.f, 0.f, 0.f);
      if (gr < M) v = *(const float4*)&A1[(size_t)gr * K1 + k0 + asg * 4];
      *(float4*)&As[arow * KT + asg * 4] = v;
    }
    {
      const float* Wrow = W1 + (size_t)bj * K1;
#pragma unroll
      for (int f = 0; f < F; ++f) {
        const float4 w = *(const float4*)&Wrow[k0 + kq + f * 4];
        const int kk = kq + f * 4;
        Bt[(kk + 0) * BTS + bj] = w.x;
        Bt[(kk + 1) * BTS + bj] = w.y;
        Bt[(kk + 2) * BTS + bj] = w.z;
        Bt[(kk + 3) * BTS + bj] = w.w;
      }
    }
    __syncthreads();
#pragma unroll
    for (int kk = 0; kk < KT; kk += 4) {
      float4 a4[RPT];
#pragma unroll
      for (int rr = 0; rr < RPT; ++rr)
        a4[rr] = *(const float4*)&As[(rbase + rr) * KT + kk];
#pragma unroll
      for (int dk = 0; dk < 4; ++dk) {
        const float4 bv = *(const float4*)&Bt[(kk + dk) * BTS + j0];
#pragma unroll
        for (int rr = 0; rr < RPT; ++rr) {
          const float av = (dk == 0)   ? a4[rr].x
                           : (dk == 1) ? a4[rr].y
                           : (dk == 2) ? a4[rr].z
                                       : a4[rr].w;
          acc[rr].x += av * bv.x;
          acc[rr].y += av * bv.y;
          acc[rr].z += av * bv.z;
          acc[rr].w += av * bv.w;
        }
      }
    }
    __syncthreads();
  }

  float4 bv4 = make_float4(0.f, 0.f, 0.f, 0.f);
  if (!DUAL) {
    bv4 = *(const float4*)&bias[j0];
  } else if (j0 >= 64) {
    bv4 = *(const float4*)&bias[j0 - 64];
  }
#pragma unroll
  for (int rr = 0; rr < RPT; ++rr) {
    const int gr = growbase + rbase + rr;
    if (gr < M) {
      float4 o = acc[rr];
      o.x += bv4.x; o.y += bv4.y; o.z += bv4.z; o.w += bv4.w;
      if (RELU) {
        o.x = fmaxf(o.x, 0.f); o.y = fmaxf(o.y, 0.f);
        o.z = fmaxf(o.z, 0.f); o.w = fmaxf(o.w, 0.f);
      }
      *(float4*)&out[(size_t)gr * COLS + j0] = o;
    }
  }
}

// ---------------- launch ----------------

extern "C" void kernel_launch(void* const* d_in, const int* in_sizes, int n_in,
                              void* d_out, int out_size, void* d_ws, size_t ws_size,
                              hipStream_t stream) {
  const float* x    = (const float*)d_in[0];
  const int*   edge = (const int*)d_in[1];
  const float* Wl1  = (const float*)d_in[2];
  const float* bl1  = (const float*)d_in[3];
  const float* Wr1  = (const float*)d_in[4];
  const float* Wl2  = (const float*)d_in[5];
  const float* bl2  = (const float*)d_in[6];
  const float* Wr2  = (const float*)d_in[7];
  const float* Wl3  = (const float*)d_in[8];
  const float* bl3  = (const float*)d_in[9];
  const float* Wr3  = (const float*)d_in[10];
  const float* Wreg = (const float*)d_in[11];
  const float* breg = (const float*)d_in[12];

  const int N = in_sizes[0] / 128;  // 50000
  const int E = in_sizes[1] / 2;    // 600000
  const int* src = edge;
  const int* dst = edge + E;

  char* ws = (char*)d_ws;
  size_t off = 0;
  auto alloc = [&](size_t bytes) {
    void* p = ws + off;
    off = (off + bytes + 255) & ~(size_t)255;
    return p;
  };
  int*   deg    = (int*)alloc((size_t)N * 4);
  int*   offs   = (int*)alloc((size_t)(N + 1) * 4);
  int*   cursor = (int*)alloc((size_t)N * 4);
  int*   csr    = (int*)alloc((size_t)E * 4);
  int*   bsums  = (int*)alloc(256 * 4);
  float* mean   = (float*)alloc((size_t)N * 128 * 4);  // also PQ buffer (layer 3)
  float* hA     = (float*)alloc((size_t)N * 128 * 4);
  float* hB     = (float*)alloc((size_t)N * 128 * 4);
  (void)ws_size;

  // --- CSR build ---
  hipMemsetAsync(deg, 0, (size_t)N * 4, stream);
  k_hist<<<2048, BLK, 0, stream>>>(dst, deg, E);
  int nb = (N + 1023) >> 10;
  k_scan1<<<nb, BLK, 0, stream>>>(deg, offs, bsums, N);
  k_scan2<<<1, 64, 0, stream>>>(bsums, nb);
  k_scan3<<<(N + BLK - 1) / BLK, BLK, 0, stream>>>(offs, bsums, cursor, N, E);
  k_fill<<<2048, BLK, 0, stream>>>(src, dst, cursor, csr, E);

  const int aggGrid = (N * 64 + BLK - 1) / BLK;
  const int gemmGrid = (N + 31) / 32;   // 32-row tiles

  // --- layer 1: h1 = relu(mean(x)@Wl1^T + x@Wr1^T + bl1) ---
  k_agg<<<aggGrid, BLK, 0, stream>>>(x, offs, csr, mean, N);
  k_linear<128, true, false><<<gemmGrid, BLK, 0, stream>>>(
      mean, Wl1, 128, x, Wr1, 128, bl1, hA, N);

  // --- layer 2 ---
  k_agg<<<aggGrid, BLK, 0, stream>>>(hA, offs, csr, mean, N);
  k_linear<128, true, false><<<gemmGrid, BLK, 0, stream>>>(
      mean, Wl2, 128, hA, Wr2, 128, bl2, hB, N);

  // --- layer 3 (transform-before-aggregate): PQ = [hB@Wl3^T | hB@Wr3^T+bl3] ---
  k_linear<128, false, true><<<gemmGrid, BLK, 0, stream>>>(
      hB, Wl3, 128, (const float*)nullptr, Wr3, 0, bl3, mean, N);
  k_agg_add<<<aggGrid, BLK, 0, stream>>>(mean, offs, csr, hA, N);

  // --- head: out = h3@Wreg^T + breg ---
  k_linear<64, false, false><<<gemmGrid, BLK, 0, stream>>>(
      hA, Wreg, 64, (const float*)nullptr, (const float*)nullptr, 0, breg,
      (float*)d_out, N);
}